// Round 1
// baseline (3051.026 us; speedup 1.0000x reference)
//
#include <hip/hip_runtime.h>
#include <hip/hip_bf16.h>
#include <math.h>

#define B_    2
#define S_    2048
#define HID_  2048
#define NH_   32
#define NKV_  4
#define HD_   64
#define LORA_ 512
#define REP_  (NH_/NKV_)
#define SCALE_ 0.125f
#define NEGV  (-1e30f)

// cos/sin table: tab[s*64 + i] = cos(pos_s * inv_freq_i), tab[s*64+32+i] = sin(...)
__global__ void rope_table_k(float* __restrict__ tab) {
    int idx = blockIdx.x * blockDim.x + threadIdx.x;   // 0 .. S_*32-1
    if (idx >= S_ * 32) return;
    int s = idx >> 5, i = idx & 31;
    float inv = 1.0f / powf(10000.0f, (float)(2 * i) / 64.0f);
    float ang = (float)s * inv;
    tab[s * 64 + i]      = cosf(ang);
    tab[s * 64 + 32 + i] = sinf(ang);
}

// fp32 SGEMM: C[M,N] = A[M,K] @ B[K,N]; M%128==0, N%128==0, K%16==0
template<int BM, int BN, int BK>
__global__ __launch_bounds__(256, 2)
void sgemm(const float* __restrict__ A, const float* __restrict__ B,
           float* __restrict__ C, int M, int N, int K) {
    __shared__ float As[BK][BM];
    __shared__ float Bs[BK][BN];
    const int tid = threadIdx.x;
    const int tx = tid & 15;        // 0..15  (col group)
    const int ty = tid >> 4;        // 0..15  (row group)
    const int row0 = blockIdx.y * BM;
    const int col0 = blockIdx.x * BN;

    float acc[8][8];
    #pragma unroll
    for (int i = 0; i < 8; ++i)
        #pragma unroll
        for (int j = 0; j < 8; ++j) acc[i][j] = 0.f;

    const int aRow = tid >> 2;          // 0..63
    const int aCol = (tid & 3) * 4;     // 0,4,8,12
    const int bRow = tid >> 5;          // 0..7
    const int bCol = (tid & 31) * 4;    // 0..124

    const float* Ap = A + (size_t)(row0 + aRow) * K + aCol;
    const float* Bp = B + (size_t)bRow * N + col0 + bCol;

    for (int k0 = 0; k0 < K; k0 += BK) {
        float4 a0 = *(const float4*)(Ap + k0);
        float4 a1 = *(const float4*)(Ap + (size_t)64 * K + k0);
        As[aCol + 0][aRow]      = a0.x;
        As[aCol + 1][aRow]      = a0.y;
        As[aCol + 2][aRow]      = a0.z;
        As[aCol + 3][aRow]      = a0.w;
        As[aCol + 0][aRow + 64] = a1.x;
        As[aCol + 1][aRow + 64] = a1.y;
        As[aCol + 2][aRow + 64] = a1.z;
        As[aCol + 3][aRow + 64] = a1.w;
        float4 b0 = *(const float4*)(Bp + (size_t)k0 * N);
        float4 b1 = *(const float4*)(Bp + (size_t)(k0 + 8) * N);
        *(float4*)&Bs[bRow][bCol]     = b0;
        *(float4*)&Bs[bRow + 8][bCol] = b1;
        __syncthreads();

        #pragma unroll
        for (int kk = 0; kk < BK; ++kk) {
            float a[8], b[8];
            #pragma unroll
            for (int i = 0; i < 8; ++i) a[i] = As[kk][ty + i * 16];
            #pragma unroll
            for (int j = 0; j < 8; ++j) b[j] = Bs[kk][tx + j * 16];
            #pragma unroll
            for (int i = 0; i < 8; ++i)
                #pragma unroll
                for (int j = 0; j < 8; ++j)
                    acc[i][j] += a[i] * b[j];
        }
        __syncthreads();
    }

    #pragma unroll
    for (int i = 0; i < 8; ++i) {
        float* Cp = C + (size_t)(row0 + ty + i * 16) * N + col0 + tx;
        #pragma unroll
        for (int j = 0; j < 8; ++j)
            Cp[j * 16] = acc[i][j];
    }
}

// Build RoPE'd K and V in (b, kvh, s, 64) layout from KV (b, s, 512)
__global__ void prep_kv_k(const float* __restrict__ kv, const float* __restrict__ tab,
                          float* __restrict__ Kr, float* __restrict__ V) {
    int idx = blockIdx.x * blockDim.x + threadIdx.x;   // B*NKV*S*32
    if (idx >= B_ * NKV_ * S_ * 32) return;
    int i = idx & 31;
    int r = idx >> 5;                  // (b*NKV + kvh)*S + s
    int s = r & (S_ - 1);
    int bk = r >> 11;                  // b*NKV + kvh
    int kvh = bk & (NKV_ - 1);
    int b = bk >> 2;
    const float* src = kv + ((size_t)(b * S_ + s)) * 512 + kvh * 128;
    float k1 = src[i], k2 = src[i + 32];
    float v1 = src[64 + i], v2 = src[96 + i];
    float c  = tab[s * 64 + i];
    float sn = tab[s * 64 + 32 + i];
    size_t dst = (size_t)r * 64;
    Kr[dst + i]      = k1 * c - k2 * sn;
    Kr[dst + 32 + i] = k2 * c + k1 * sn;
    V[dst + i]       = v1;
    V[dst + 32 + i]  = v2;
}

// Causal GQA attention. 1 thread = 1 q row. Block = 256 rows of one (b,h).
// grid = (S/256, NH, B)
__global__ __launch_bounds__(256, 1)
void attn_k(const float* __restrict__ hs, const float* __restrict__ tab,
            const float* __restrict__ Kr, const float* __restrict__ Vv,
            float* __restrict__ out) {
    const int qc = blockIdx.x, h = blockIdx.y, b = blockIdx.z;
    const int t = threadIdx.x;
    const int q = qc * 256 + t;
    const int kvh = h / REP_;

    __shared__ float Ks[64][64];
    __shared__ float Vs[64][64];

    // load q row + apply RoPE
    float qreg[64];
    const float* hq = hs + ((size_t)(b * S_ + q)) * HID_ + h * HD_;
    const float* ct = tab + (size_t)q * 64;
    #pragma unroll
    for (int i = 0; i < 32; ++i) {
        float x1 = hq[i], x2 = hq[i + 32];
        float c = ct[i], sn = ct[32 + i];
        qreg[i]      = x1 * c - x2 * sn;
        qreg[i + 32] = x2 * c + x1 * sn;
    }

    float o[64];
    #pragma unroll
    for (int d = 0; d < 64; ++d) o[d] = 0.f;
    float m = -INFINITY, l = 0.f;

    const float* Kbase = Kr + ((size_t)(b * NKV_ + kvh)) * S_ * 64;
    const float* Vbase = Vv + ((size_t)(b * NKV_ + kvh)) * S_ * 64;

    const int qmax = qc * 256 + 255;
    const int ntile = qmax / 64 + 1;

    for (int kt = 0; kt < ntile; ++kt) {
        const int k0 = kt * 64;
        // stage K/V tiles (64x64 floats each)
        #pragma unroll
        for (int r = 0; r < 4; ++r) {
            int off = r * 1024 + t * 4;
            *(float4*)&Ks[0][off] = *(const float4*)&Kbase[(size_t)k0 * 64 + off];
            *(float4*)&Vs[0][off] = *(const float4*)&Vbase[(size_t)k0 * 64 + off];
        }
        __syncthreads();

        const bool full = (k0 + 63 <= q);
        // 4 chunks of 16 scores, registers only
        #pragma unroll 1
        for (int c4 = 0; c4 < 4; ++c4) {
            float sreg[16];
            float tm = -INFINITY;
            #pragma unroll
            for (int kk2 = 0; kk2 < 16; ++kk2) {
                int kk = c4 * 16 + kk2;
                float sacc = 0.f;
                #pragma unroll
                for (int d = 0; d < 64; ++d) sacc += qreg[d] * Ks[kk][d];
                sacc *= SCALE_;
                if (!full && (k0 + kk > q)) sacc = NEGV;
                sreg[kk2] = sacc;
                tm = fmaxf(tm, sacc);
            }
            float mn = fmaxf(m, tm);
            float cf = expf(m - mn);
            l *= cf;
            #pragma unroll
            for (int d = 0; d < 64; ++d) o[d] *= cf;
            #pragma unroll
            for (int kk2 = 0; kk2 < 16; ++kk2) {
                float p = expf(sreg[kk2] - mn);
                l += p;
                int kk = c4 * 16 + kk2;
                #pragma unroll
                for (int d = 0; d < 64; ++d) o[d] += p * Vs[kk][d];
            }
            m = mn;
        }
        __syncthreads();
    }

    float inv = 1.f / l;
    float* op = out + ((size_t)(b * S_ + q)) * (NH_ * HD_) + h * HD_;
    #pragma unroll
    for (int d = 0; d < 64; d += 4) {
        float4 v4 = { o[d] * inv, o[d+1] * inv, o[d+2] * inv, o[d+3] * inv };
        *(float4*)&op[d] = v4;
    }
}

extern "C" void kernel_launch(void* const* d_in, const int* in_sizes, int n_in,
                              void* d_out, int out_size, void* d_ws, size_t ws_size,
                              hipStream_t stream) {
    const float* hs   = (const float*)d_in[0];
    const float* kv_a = (const float*)d_in[1];
    const float* kv_b = (const float*)d_in[2];
    const float* o_w  = (const float*)d_in[3];
    float* out = (float*)d_out;
    float* ws  = (float*)d_ws;

    float* tab = ws;                       // 131072 floats
    float* C1  = tab + 131072;             // 4096*512 = 2097152
    float* KV  = C1  + 2097152;            // 2097152
    float* Kr  = KV  + 2097152;            // 2*4*2048*64 = 1048576
    float* Vv  = Kr  + 1048576;            // 1048576
    float* AO  = Vv  + 1048576;            // 4096*2048 = 8388608

    rope_table_k<<<dim3(256), dim3(256), 0, stream>>>(tab);

    // C1 = hs @ kv_a : (4096 x 2048) @ (2048 x 512)
    sgemm<128,128,16><<<dim3(512/128, 4096/128), dim3(256), 0, stream>>>(hs, kv_a, C1, 4096, 512, 2048);
    // KV = C1 @ kv_b : (4096 x 512) @ (512 x 512)
    sgemm<128,128,16><<<dim3(512/128, 4096/128), dim3(256), 0, stream>>>(C1, kv_b, KV, 4096, 512, 512);

    prep_kv_k<<<dim3((B_*NKV_*S_*32)/256), dim3(256), 0, stream>>>(KV, tab, Kr, Vv);

    attn_k<<<dim3(S_/256, NH_, B_), dim3(256), 0, stream>>>(hs, tab, Kr, Vv, AO);

    // out = AO @ o_w : (4096 x 2048) @ (2048 x 2048)
    sgemm<128,128,16><<<dim3(2048/128, 4096/128), dim3(256), 0, stream>>>(AO, o_w, out, 4096, 2048, 2048);
}

// Round 2
// 451.742 us; speedup vs baseline: 6.7539x; 6.7539x over previous
//
#include <hip/hip_runtime.h>
#include <hip/hip_bf16.h>
#include <math.h>

#define B_    2
#define S_    2048
#define HID_  2048
#define NH_   32
#define NKV_  4
#define HD_   64
#define NEGV  (-1e30f)

typedef __attribute__((ext_vector_type(8))) short bfrag;
typedef __attribute__((ext_vector_type(4))) float f32x4;

__device__ __forceinline__ short f2bf(float f) {
    unsigned u = __builtin_bit_cast(unsigned, f);
    u += 0x7FFFu + ((u >> 16) & 1u);
    return (short)(u >> 16);
}

// cos/sin table: tab[s*64+i]=cos, tab[s*64+32+i]=sin
__global__ void rope_table_k(float* __restrict__ tab) {
    int idx = blockIdx.x * blockDim.x + threadIdx.x;
    if (idx >= S_ * 32) return;
    int s = idx >> 5, i = idx & 31;
    float inv = 1.0f / powf(10000.0f, (float)(2 * i) / 64.0f);
    float ang = (float)s * inv;
    tab[s * 64 + i]      = cosf(ang);
    tab[s * 64 + 32 + i] = sinf(ang);
}

// fp32 -> bf16 elementwise (n must be multiple of 1024*... grid sized exactly)
__global__ void f2b_k(const float* __restrict__ in, short* __restrict__ out) {
    int i = (blockIdx.x * blockDim.x + threadIdx.x) * 4;
    float4 v = *(const float4*)(in + i);
    short4 o;
    o.x = f2bf(v.x); o.y = f2bf(v.y); o.z = f2bf(v.z); o.w = f2bf(v.w);
    *(short4*)(out + i) = o;
}

// fp32 (R x C) -> bf16 transposed (C x R)
__global__ void transpose_f2b(const float* __restrict__ in, short* __restrict__ out,
                              int R, int C) {
    __shared__ float t[32][33];
    int c0 = blockIdx.x * 32, r0 = blockIdx.y * 32;
    int x = threadIdx.x, y = threadIdx.y;  // 32 x 8
    #pragma unroll
    for (int i = 0; i < 32; i += 8) t[y + i][x] = in[(size_t)(r0 + y + i) * C + c0 + x];
    __syncthreads();
    #pragma unroll
    for (int i = 0; i < 32; i += 8)
        out[(size_t)(c0 + y + i) * R + r0 + x] = f2bf(t[x][y + i]);
}

// bf16 batched transpose: per slice z, in (R x C) -> out (C x R)
__global__ void transpose_b2b(const short* __restrict__ in, short* __restrict__ out,
                              int R, int C) {
    const short* ib = in + (size_t)blockIdx.z * R * C;
    short* ob = out + (size_t)blockIdx.z * R * C;
    __shared__ short t[32][33];
    int c0 = blockIdx.x * 32, r0 = blockIdx.y * 32;
    int x = threadIdx.x, y = threadIdx.y;
    #pragma unroll
    for (int i = 0; i < 32; i += 8) t[y + i][x] = ib[(size_t)(r0 + y + i) * C + c0 + x];
    __syncthreads();
    #pragma unroll
    for (int i = 0; i < 32; i += 8)
        ob[(size_t)(c0 + y + i) * R + r0 + x] = t[x][y + i];
}

// KV fp32 (b,s,512) -> RoPE'd K bf16 (b,kvh,s,64) + V bf16 (b,kvh,s,64)
__global__ void prep_kv_k(const float* __restrict__ kv, const float* __restrict__ tab,
                          short* __restrict__ Kr, short* __restrict__ Vv) {
    int idx = blockIdx.x * blockDim.x + threadIdx.x;
    int i = idx & 31;
    int r = idx >> 5;
    int s = r & (S_ - 1);
    int bk = r >> 11;
    int kvh = bk & (NKV_ - 1);
    int b = bk >> 2;
    const float* src = kv + ((size_t)(b * S_ + s)) * 512 + kvh * 128;
    float k1 = src[i], k2 = src[i + 32];
    float v1 = src[64 + i], v2 = src[96 + i];
    float c = tab[s * 64 + i], sn = tab[s * 64 + 32 + i];
    size_t dst = (size_t)r * 64;
    Kr[dst + i]      = f2bf(k1 * c - k2 * sn);
    Kr[dst + 32 + i] = f2bf(k2 * c + k1 * sn);
    Vv[dst + i]      = f2bf(v1);
    Vv[dst + 32 + i] = f2bf(v2);
}

// bf16 MFMA GEMM: C[M,N] = A[M,K] (row-major) @ Bt[N,K]^T. 128x128 tile, BK=32.
template<bool OUT_BF16>
__global__ __launch_bounds__(256)
void mgemm(const short* __restrict__ A, const short* __restrict__ Bt,
           void* __restrict__ Cout, int M, int N, int K) {
    __shared__ short As[128][32];
    __shared__ short Bs[128][32];
    const int tid = threadIdx.x;
    const int wv = tid >> 6, lane = tid & 63;
    const int g = lane >> 4, r = lane & 15;
    const int wr = wv >> 1, wc = wv & 1;
    const int row0 = blockIdx.y * 128;
    const int col0 = blockIdx.x * 128;

    f32x4 acc[4][4];
    #pragma unroll
    for (int i = 0; i < 4; ++i)
        #pragma unroll
        for (int j = 0; j < 4; ++j) { f32x4 z = {0.f,0.f,0.f,0.f}; acc[i][j] = z; }

    const int srow = tid >> 2;          // 0..63
    const int schk = (tid & 3) * 8;     // 0,8,16,24

    for (int k0 = 0; k0 < K; k0 += 32) {
        bfrag a0 = *(const bfrag*)(A + (size_t)(row0 + srow) * K + k0 + schk);
        bfrag a1 = *(const bfrag*)(A + (size_t)(row0 + srow + 64) * K + k0 + schk);
        bfrag b0 = *(const bfrag*)(Bt + (size_t)(col0 + srow) * K + k0 + schk);
        bfrag b1 = *(const bfrag*)(Bt + (size_t)(col0 + srow + 64) * K + k0 + schk);
        __syncthreads();
        *(bfrag*)&As[srow][schk] = a0;
        *(bfrag*)&As[srow + 64][schk] = a1;
        *(bfrag*)&Bs[srow][schk] = b0;
        *(bfrag*)&Bs[srow + 64][schk] = b1;
        __syncthreads();
        bfrag af[4], bf[4];
        #pragma unroll
        for (int i = 0; i < 4; ++i) af[i] = *(const bfrag*)&As[wr * 64 + i * 16 + r][g * 8];
        #pragma unroll
        for (int j = 0; j < 4; ++j) bf[j] = *(const bfrag*)&Bs[wc * 64 + j * 16 + r][g * 8];
        #pragma unroll
        for (int i = 0; i < 4; ++i)
            #pragma unroll
            for (int j = 0; j < 4; ++j)
                acc[i][j] = __builtin_amdgcn_mfma_f32_16x16x32_bf16(af[i], bf[j], acc[i][j], 0, 0, 0);
    }

    #pragma unroll
    for (int i = 0; i < 4; ++i) {
        int row = row0 + wr * 64 + i * 16 + g * 4;
        #pragma unroll
        for (int j = 0; j < 4; ++j) {
            int col = col0 + wc * 64 + j * 16 + r;
            #pragma unroll
            for (int q = 0; q < 4; ++q) {
                float v = acc[i][j][q];
                if (OUT_BF16) ((short*)Cout)[(size_t)(row + q) * N + col] = f2bf(v);
                else          ((float*)Cout)[(size_t)(row + q) * N + col] = v;
            }
        }
    }
}

// Flash attention, bf16 MFMA. Block = 4 waves = 64 q rows of one (b,h).
// grid (S/64, NH, B). Kr: (b,kvh,s,64) bf16, Vt: (b,kvh,64,s) bf16.
__global__ __launch_bounds__(256)
void attn_mfma(const float* __restrict__ hs, const float* __restrict__ tab,
               const short* __restrict__ Kr, const short* __restrict__ Vt,
               short* __restrict__ AO) {
    const int qc = blockIdx.x, h = blockIdx.y, b = blockIdx.z;
    const int kvh = h >> 3;
    const int tid = threadIdx.x;
    const int wv = tid >> 6, lane = tid & 63;
    const int g = lane >> 4, r = lane & 15;

    __shared__ short Ks[64][72];
    __shared__ short Vs[64][72];
    __shared__ short Ps[4][16][72];

    // Q A-frags: row = lane&15 within wave's 16 rows; RoPE + 0.125 scale folded.
    {
    }
    const int qg = qc * 64 + wv * 16 + r;
    const float* hq = hs + ((size_t)(b * S_ + qg)) * HID_ + h * HD_;
    const float* ct = tab + (size_t)qg * 64;
    bfrag qf0, qf1;
    #pragma unroll
    for (int j = 0; j < 8; ++j) {
        int i = g * 8 + j;
        float x1 = hq[i], x2 = hq[i + 32];
        float c = ct[i], sn = ct[32 + i];
        qf0[j] = f2bf((x1 * c - x2 * sn) * 0.125f);
        qf1[j] = f2bf((x2 * c + x1 * sn) * 0.125f);
    }

    f32x4 oacc[4];
    #pragma unroll
    for (int i = 0; i < 4; ++i) { f32x4 z = {0.f,0.f,0.f,0.f}; oacc[i] = z; }
    float m[4], l[4];
    #pragma unroll
    for (int i = 0; i < 4; ++i) { m[i] = NEGV; l[i] = 0.f; }

    const size_t kbase = ((size_t)(b * NKV_ + kvh)) * S_ * 64;
    const size_t vbase = ((size_t)(b * NKV_ + kvh)) * 64 * S_;
    const int ntile = qc + 1;
    const int qrow0 = qc * 64 + wv * 16 + g * 4;   // this lane's D rows (+p)

    const int strow = tid >> 2, stq = (tid & 3) * 16;

    for (int kt = 0; kt < ntile; ++kt) {
        const int k0 = kt * 64;
        bfrag k8a = *(const bfrag*)(Kr + kbase + (size_t)(k0 + strow) * 64 + stq);
        bfrag k8b = *(const bfrag*)(Kr + kbase + (size_t)(k0 + strow) * 64 + stq + 8);
        bfrag v8a = *(const bfrag*)(Vt + vbase + (size_t)strow * S_ + k0 + stq);
        bfrag v8b = *(const bfrag*)(Vt + vbase + (size_t)strow * S_ + k0 + stq + 8);
        __syncthreads();
        *(bfrag*)&Ks[strow][stq] = k8a;
        *(bfrag*)&Ks[strow][stq + 8] = k8b;
        *(bfrag*)&Vs[strow][stq] = v8a;
        *(bfrag*)&Vs[strow][stq + 8] = v8b;
        __syncthreads();

        // QK^T: D rows = q (g*4+p), cols = kv (nt*16 + r)
        f32x4 sacc[4];
        #pragma unroll
        for (int nt = 0; nt < 4; ++nt) {
            f32x4 z = {0.f,0.f,0.f,0.f};
            bfrag kf0 = *(const bfrag*)&Ks[nt * 16 + r][g * 8];
            bfrag kf1 = *(const bfrag*)&Ks[nt * 16 + r][32 + g * 8];
            z = __builtin_amdgcn_mfma_f32_16x16x32_bf16(qf0, kf0, z, 0, 0, 0);
            z = __builtin_amdgcn_mfma_f32_16x16x32_bf16(qf1, kf1, z, 0, 0, 0);
            sacc[nt] = z;
        }
        // causal mask
        #pragma unroll
        for (int nt = 0; nt < 4; ++nt) {
            int kv = k0 + nt * 16 + r;
            #pragma unroll
            for (int p = 0; p < 4; ++p)
                if (kv > qrow0 + p) sacc[nt][p] = NEGV;
        }
        // online softmax (16-lane row reduce)
        #pragma unroll
        for (int p = 0; p < 4; ++p) {
            float v = fmaxf(fmaxf(sacc[0][p], sacc[1][p]), fmaxf(sacc[2][p], sacc[3][p]));
            #pragma unroll
            for (int sh = 1; sh < 16; sh <<= 1) v = fmaxf(v, __shfl_xor(v, sh, 64));
            float mn = fmaxf(m[p], v);
            float cf = expf(m[p] - mn);
            m[p] = mn;
            float ps = 0.f;
            #pragma unroll
            for (int nt = 0; nt < 4; ++nt) {
                float e = expf(sacc[nt][p] - mn);
                sacc[nt][p] = e;
                ps += e;
            }
            #pragma unroll
            for (int sh = 1; sh < 16; sh <<= 1) ps += __shfl_xor(ps, sh, 64);
            l[p] = l[p] * cf + ps;
            #pragma unroll
            for (int nt = 0; nt < 4; ++nt) oacc[nt][p] *= cf;
        }
        // P -> LDS (A-frag layout for PV)
        #pragma unroll
        for (int nt = 0; nt < 4; ++nt)
            #pragma unroll
            for (int p = 0; p < 4; ++p)
                Ps[wv][g * 4 + p][nt * 16 + r] = f2bf(sacc[nt][p]);
        __syncthreads();
        // PV: O(16q x 64d) += P(16q x 64kv) @ V(64kv x 64d)
        bfrag pf0 = *(const bfrag*)&Ps[wv][r][g * 8];
        bfrag pf1 = *(const bfrag*)&Ps[wv][r][32 + g * 8];
        #pragma unroll
        for (int nt = 0; nt < 4; ++nt) {
            bfrag vf0 = *(const bfrag*)&Vs[nt * 16 + r][g * 8];
            bfrag vf1 = *(const bfrag*)&Vs[nt * 16 + r][32 + g * 8];
            oacc[nt] = __builtin_amdgcn_mfma_f32_16x16x32_bf16(pf0, vf0, oacc[nt], 0, 0, 0);
            oacc[nt] = __builtin_amdgcn_mfma_f32_16x16x32_bf16(pf1, vf1, oacc[nt], 0, 0, 0);
        }
        __syncthreads();
    }

    #pragma unroll
    for (int p = 0; p < 4; ++p) {
        float inv = 1.f / l[p];
        int qrow = qrow0 + p;
        short* op = AO + ((size_t)(b * S_ + qrow)) * (NH_ * HD_) + h * HD_;
        #pragma unroll
        for (int nt = 0; nt < 4; ++nt)
            op[nt * 16 + r] = f2bf(oacc[nt][p] * inv);
    }
}

extern "C" void kernel_launch(void* const* d_in, const int* in_sizes, int n_in,
                              void* d_out, int out_size, void* d_ws, size_t ws_size,
                              hipStream_t stream) {
    const float* hs   = (const float*)d_in[0];
    const float* kv_a = (const float*)d_in[1];
    const float* kv_b = (const float*)d_in[2];
    const float* o_w  = (const float*)d_in[3];
    float* out = (float*)d_out;
    char* w = (char*)d_ws;

    float* tab   = (float*)w;                 w += 524288;       // 2048*64 f32
    short* hs_bf = (short*)w;                 // 4096*2048 bf16 (aliased by AO later)
    short* AO    = (short*)w;                 w += 16777216;
    short* kvaT  = (short*)w;                 w += 2097152;      // 512 x 2048
    short* kvbT  = (short*)w;                 w += 524288;       // 512 x 512
    short* owT   = (short*)w;                 w += 8388608;      // 2048 x 2048
    short* C1    = (short*)w;                 w += 4194304;      // 4096 x 512 bf16
    float* KV    = (float*)w;                 w += 8388608;      // 4096 x 512 f32
    short* Kr    = (short*)w;                 w += 2097152;      // 2*4*2048*64
    short* Vv    = (short*)w;                 w += 2097152;
    short* Vt    = (short*)w;                 w += 2097152;

    rope_table_k<<<dim3(256), dim3(256), 0, stream>>>(tab);
    f2b_k<<<dim3(8192), dim3(256), 0, stream>>>(hs, hs_bf);  // 4096*2048/4/256

    transpose_f2b<<<dim3(16, 64), dim3(32, 8), 0, stream>>>(kv_a, kvaT, 2048, 512);
    transpose_f2b<<<dim3(16, 16), dim3(32, 8), 0, stream>>>(kv_b, kvbT, 512, 512);
    transpose_f2b<<<dim3(64, 64), dim3(32, 8), 0, stream>>>(o_w, owT, 2048, 2048);

    // C1 = hs @ kv_a  (4096 x 512, K=2048), bf16 out
    mgemm<true><<<dim3(4, 32), dim3(256), 0, stream>>>(hs_bf, kvaT, C1, 4096, 512, 2048);
    // KV = C1 @ kv_b  (4096 x 512, K=512), f32 out
    mgemm<false><<<dim3(4, 32), dim3(256), 0, stream>>>(C1, kvbT, KV, 4096, 512, 512);

    prep_kv_k<<<dim3(2048), dim3(256), 0, stream>>>(KV, tab, Kr, Vv);
    // Vt slices: (2048 x 64) -> (64 x 2048), 8 slices
    transpose_b2b<<<dim3(2, 64, 8), dim3(32, 8), 0, stream>>>(Vv, Vt, 2048, 64);

    attn_mfma<<<dim3(32, 32, 2), dim3(256), 0, stream>>>(hs, tab, Kr, Vt, AO);

    // out = AO @ o_w  (4096 x 2048, K=2048), f32 out
    mgemm<false><<<dim3(16, 32), dim3(256), 0, stream>>>(AO, owT, out, 4096, 2048, 2048);
}

// Round 3
// 291.102 us; speedup vs baseline: 10.4810x; 1.5518x over previous
//
#include <hip/hip_runtime.h>
#include <hip/hip_bf16.h>
#include <math.h>

#define B_    2
#define S_    2048
#define HID_  2048
#define NH_   32
#define NKV_  4
#define HD_   64
#define NEGV  (-1e30f)

typedef __attribute__((ext_vector_type(8))) short bfrag;
typedef __attribute__((ext_vector_type(4))) float f32x4;

__device__ __forceinline__ short f2bf(float f) {
    unsigned u = __builtin_bit_cast(unsigned, f);
    u += 0x7FFFu + ((u >> 16) & 1u);
    return (short)(u >> 16);
}

__device__ __forceinline__ void glds16(const short* g, short* l) {
    __builtin_amdgcn_global_load_lds(
        (const __attribute__((address_space(1))) void*)(const void*)g,
        (__attribute__((address_space(3))) void*)(void*)l, 16, 0, 0);
}

// cos/sin table: tab[s*64+i]=cos, tab[s*64+32+i]=sin
__global__ void rope_table_k(float* __restrict__ tab) {
    int idx = blockIdx.x * blockDim.x + threadIdx.x;
    if (idx >= S_ * 32) return;
    int s = idx >> 5, i = idx & 31;
    float inv = 1.0f / powf(10000.0f, (float)(2 * i) / 64.0f);
    float ang = (float)s * inv;
    tab[s * 64 + i]      = cosf(ang);
    tab[s * 64 + 32 + i] = sinf(ang);
}

__global__ void f2b_k(const float* __restrict__ in, short* __restrict__ out) {
    int i = (blockIdx.x * blockDim.x + threadIdx.x) * 4;
    float4 v = *(const float4*)(in + i);
    short4 o;
    o.x = f2bf(v.x); o.y = f2bf(v.y); o.z = f2bf(v.z); o.w = f2bf(v.w);
    *(short4*)(out + i) = o;
}

// fp32 (R x C) -> bf16 transposed (C x R)
__global__ void transpose_f2b(const float* __restrict__ in, short* __restrict__ out,
                              int R, int C) {
    __shared__ float t[32][33];
    int c0 = blockIdx.x * 32, r0 = blockIdx.y * 32;
    int x = threadIdx.x, y = threadIdx.y;  // 32 x 8
    #pragma unroll
    for (int i = 0; i < 32; i += 8) t[y + i][x] = in[(size_t)(r0 + y + i) * C + c0 + x];
    __syncthreads();
    #pragma unroll
    for (int i = 0; i < 32; i += 8)
        out[(size_t)(c0 + y + i) * R + r0 + x] = f2bf(t[x][y + i]);
}

// KV fp32 (b,s,512) -> RoPE'd K bf16 (b,kvh,s,64) XOR-swizzled + V bf16 natural
__global__ void prep_kv_k(const float* __restrict__ kv, const float* __restrict__ tab,
                          short* __restrict__ Kr, short* __restrict__ Vv) {
    int idx = blockIdx.x * blockDim.x + threadIdx.x;
    int i = idx & 31;
    int r = idx >> 5;
    int s = r & (S_ - 1);
    int bk = r >> 11;
    int kvh = bk & (NKV_ - 1);
    int b = bk >> 2;
    const float* src = kv + ((size_t)(b * S_ + s)) * 512 + kvh * 128;
    float k1 = src[i], k2 = src[i + 32];
    float v1 = src[64 + i], v2 = src[96 + i];
    float c = tab[s * 64 + i], sn = tab[s * 64 + 32 + i];
    size_t dst = (size_t)r * 64;
    int swz = (s & 7) << 3;
    Kr[dst + (i ^ swz)]        = f2bf(k1 * c - k2 * sn);
    Kr[dst + ((i + 32) ^ swz)] = f2bf(k2 * c + k1 * sn);
    Vv[dst + i]      = f2bf(v1);
    Vv[dst + 32 + i] = f2bf(v2);
}

// Build blocked V: Vb[(bk,kt)][d=64][c=64], where column c holds V[kv=sigma(c)][d],
// XOR-swizzled by row d. sigma(c) matches the PV A-frag kv-slot permutation.
__global__ void build_vb(const short* __restrict__ Vv, short* __restrict__ Vb) {
    int kt = blockIdx.x, bk = blockIdx.y;
    const short* src = Vv + ((size_t)bk * S_ + kt * 64) * 64;
    short* dst = Vb + ((size_t)(bk * 32 + kt)) * 4096;
    int t = threadIdx.x;
    int d = t >> 2;
    int cb = (t & 3) * 16;
    int swz = (d & 7) << 3;
    #pragma unroll
    for (int ii = 0; ii < 16; ++ii) {
        int c = cb + ii;
        int kvl = (c & 3) | (((c >> 3) & 3) << 2) | (((c >> 2) & 1) << 4) | (c & 32);
        dst[d * 64 + (c ^ swz)] = src[(size_t)kvl * 64 + d];
    }
}

// bf16 MFMA GEMM: C[M,N] = A[M,K] (row-major) @ Bt[N,K]^T. 128x128 tile, BK=32,
// global_load_lds staging (m97 structure).
template<bool OUT_BF16>
__global__ __launch_bounds__(256)
void mgemm(const short* __restrict__ A, const short* __restrict__ Bt,
           void* __restrict__ Cout, int M, int N, int K) {
    __shared__ short As[128][32];
    __shared__ short Bs[128][32];
    const int tid = threadIdx.x;
    const int wv = tid >> 6, lane = tid & 63;
    const int g = lane >> 4, r = lane & 15;
    const int wr = wv >> 1, wc = wv & 1;
    const int row0 = blockIdx.y * 128;
    const int col0 = blockIdx.x * 128;

    f32x4 acc[4][4];
    #pragma unroll
    for (int i = 0; i < 4; ++i)
        #pragma unroll
        for (int j = 0; j < 4; ++j) { f32x4 z = {0.f,0.f,0.f,0.f}; acc[i][j] = z; }

    const int srow = tid >> 2;          // 0..63
    const int schk = (tid & 3) * 8;     // 0,8,16,24
    const short* Asrc = A + (size_t)(row0 + srow) * K + schk;
    const short* Bsrc = Bt + (size_t)(col0 + srow) * K + schk;
    short* lA0 = &As[srow][schk];
    short* lA1 = &As[srow + 64][schk];
    short* lB0 = &Bs[srow][schk];
    short* lB1 = &Bs[srow + 64][schk];

    for (int k0 = 0; k0 < K; k0 += 32) {
        __syncthreads();
        glds16(Asrc + k0, lA0);
        glds16(Asrc + (size_t)64 * K + k0, lA1);
        glds16(Bsrc + k0, lB0);
        glds16(Bsrc + (size_t)64 * K + k0, lB1);
        __syncthreads();
        bfrag af[4], bf[4];
        #pragma unroll
        for (int i = 0; i < 4; ++i) af[i] = *(const bfrag*)&As[wr * 64 + i * 16 + r][g * 8];
        #pragma unroll
        for (int j = 0; j < 4; ++j) bf[j] = *(const bfrag*)&Bs[wc * 64 + j * 16 + r][g * 8];
        #pragma unroll
        for (int i = 0; i < 4; ++i)
            #pragma unroll
            for (int j = 0; j < 4; ++j)
                acc[i][j] = __builtin_amdgcn_mfma_f32_16x16x32_bf16(af[i], bf[j], acc[i][j], 0, 0, 0);
    }

    #pragma unroll
    for (int i = 0; i < 4; ++i) {
        int row = row0 + wr * 64 + i * 16 + g * 4;
        #pragma unroll
        for (int j = 0; j < 4; ++j) {
            int col = col0 + wc * 64 + j * 16 + r;
            #pragma unroll
            for (int q = 0; q < 4; ++q) {
                float v = acc[i][j][q];
                if (OUT_BF16) ((short*)Cout)[(size_t)(row + q) * N + col] = f2bf(v);
                else          ((float*)Cout)[(size_t)(row + q) * N + col] = v;
            }
        }
    }
}

// Flash attention, swapped-QK^T bf16 MFMA. Block = 4 waves; wave = 32 q rows
// (2 subtiles of 16). grid (S/128, NH, B). Kr swizzled (b,kvh,s,64); Vb blocked.
__global__ __launch_bounds__(256)
void attn_mfma(const float* __restrict__ hs, const float* __restrict__ tab,
               const short* __restrict__ Kr, const short* __restrict__ Vb,
               short* __restrict__ AO) {
    const int qc = (int)gridDim.x - 1 - (int)blockIdx.x;   // long blocks first
    const int h = blockIdx.y, b = blockIdx.z;
    const int kvh = h >> 3;
    const int tid = threadIdx.x;
    const int wv = tid >> 6, lane = tid & 63;
    const int g = lane >> 4, r = lane & 15;

    __shared__ short Ks[4096];
    __shared__ short Vs[4096];

    const int qbase = qc * 128 + wv * 32;

    // Q fragments (RoPE + scale folded), subtile u, d-half hh
    bfrag qf[2][2];
    #pragma unroll
    for (int u = 0; u < 2; ++u) {
        int q = qbase + u * 16 + r;
        const float* hq = hs + ((size_t)(b * S_ + q)) * HID_ + h * HD_;
        const float* ct = tab + (size_t)q * 64;
        float4 x1a = *(const float4*)(hq + g * 8);
        float4 x1b = *(const float4*)(hq + g * 8 + 4);
        float4 x2a = *(const float4*)(hq + 32 + g * 8);
        float4 x2b = *(const float4*)(hq + 32 + g * 8 + 4);
        float4 ca  = *(const float4*)(ct + g * 8);
        float4 cb  = *(const float4*)(ct + g * 8 + 4);
        float4 sa4 = *(const float4*)(ct + 32 + g * 8);
        float4 sb4 = *(const float4*)(ct + 32 + g * 8 + 4);
        float x1[8] = {x1a.x,x1a.y,x1a.z,x1a.w,x1b.x,x1b.y,x1b.z,x1b.w};
        float x2[8] = {x2a.x,x2a.y,x2a.z,x2a.w,x2b.x,x2b.y,x2b.z,x2b.w};
        float cc[8] = {ca.x,ca.y,ca.z,ca.w,cb.x,cb.y,cb.z,cb.w};
        float ss[8] = {sa4.x,sa4.y,sa4.z,sa4.w,sb4.x,sb4.y,sb4.z,sb4.w};
        #pragma unroll
        for (int j = 0; j < 8; ++j) {
            qf[u][0][j] = f2bf((x1[j] * cc[j] - x2[j] * ss[j]) * 0.125f);
            qf[u][1][j] = f2bf((x2[j] * cc[j] + x1[j] * ss[j]) * 0.125f);
        }
    }

    f32x4 oacc[2][4];
    #pragma unroll
    for (int u = 0; u < 2; ++u)
        #pragma unroll
        for (int i = 0; i < 4; ++i) { f32x4 z = {0.f,0.f,0.f,0.f}; oacc[u][i] = z; }
    float m[2] = {NEGV, NEGV}, l[2] = {0.f, 0.f};

    const short* ksrc = Kr + ((size_t)(b * NKV_ + kvh)) * S_ * 64;
    const short* vsrc = Vb + ((size_t)(b * NKV_ + kvh)) * 32 * 4096;
    const int ntile = qc * 2 + 2;

    for (int kt = 0; kt < ntile; ++kt) {
        const int k0 = kt * 64;
        __syncthreads();
        glds16(ksrc + (size_t)kt * 4096 + tid * 8,        &Ks[tid * 8]);
        glds16(ksrc + (size_t)kt * 4096 + 2048 + tid * 8, &Ks[2048 + tid * 8]);
        glds16(vsrc + (size_t)kt * 4096 + tid * 8,        &Vs[tid * 8]);
        glds16(vsrc + (size_t)kt * 4096 + 2048 + tid * 8, &Vs[2048 + tid * 8]);
        __syncthreads();

        #pragma unroll
        for (int u = 0; u < 2; ++u) {
            if (k0 > qbase + u * 16 + 15) continue;   // fully masked subtile
            const int qg = qbase + u * 16 + r;
            // QK^T swapped: A=K rows(kv), B=Q cols(q)
            f32x4 sa[4];
            #pragma unroll
            for (int nt = 0; nt < 4; ++nt) {
                int row = nt * 16 + r;
                int sw = (row & 7) << 3;
                bfrag kf0 = *(const bfrag*)&Ks[row * 64 + ((g * 8) ^ sw)];
                bfrag kf1 = *(const bfrag*)&Ks[row * 64 + ((32 + g * 8) ^ sw)];
                f32x4 z = {0.f,0.f,0.f,0.f};
                z = __builtin_amdgcn_mfma_f32_16x16x32_bf16(kf0, qf[u][0], z, 0, 0, 0);
                z = __builtin_amdgcn_mfma_f32_16x16x32_bf16(kf1, qf[u][1], z, 0, 0, 0);
                sa[nt] = z;
            }
            // causal mask (only near diagonal)
            if (k0 + 63 > qbase + u * 16) {
                #pragma unroll
                for (int nt = 0; nt < 4; ++nt) {
                    #pragma unroll
                    for (int p = 0; p < 4; ++p) {
                        int kvg = k0 + nt * 16 + 4 * g + p;
                        if (kvg > qg) sa[nt][p] = NEGV;
                    }
                }
            }
            // online softmax: per-q (col) over kv; replicas across 4 lane-groups
            float tm = NEGV;
            #pragma unroll
            for (int nt = 0; nt < 4; ++nt)
                #pragma unroll
                for (int p = 0; p < 4; ++p) tm = fmaxf(tm, sa[nt][p]);
            tm = fmaxf(tm, __shfl_xor(tm, 16, 64));
            tm = fmaxf(tm, __shfl_xor(tm, 32, 64));
            float mn = fmaxf(m[u], tm);
            float cf = __expf(m[u] - mn);
            m[u] = mn;
            float sum = 0.f;
            #pragma unroll
            for (int nt = 0; nt < 4; ++nt)
                #pragma unroll
                for (int p = 0; p < 4; ++p) {
                    float e = __expf(sa[nt][p] - mn);
                    sa[nt][p] = e;
                    sum += e;
                }
            sum += __shfl_xor(sum, 16, 64);
            sum += __shfl_xor(sum, 32, 64);
            l[u] = l[u] * cf + sum;
            // pack P into A-frags (kv-slot order sigma matches Vb permutation)
            bfrag pa0, pa1;
            #pragma unroll
            for (int j = 0; j < 8; ++j) {
                pa0[j] = f2bf(sa[j >> 2][j & 3]);
                pa1[j] = f2bf(sa[2 + (j >> 2)][j & 3]);
            }
            // rescale O (rows q = 4g+p): fetch cf of that q
            float cfp[4];
            #pragma unroll
            for (int p = 0; p < 4; ++p) cfp[p] = __shfl(cf, 20 * g + p, 64);
            #pragma unroll
            for (int nt = 0; nt < 4; ++nt)
                #pragma unroll
                for (int p = 0; p < 4; ++p) oacc[u][nt][p] *= cfp[p];
            // PV: A=P(q x kv), B=V(kv x d) from blocked Vb
            #pragma unroll
            for (int nt = 0; nt < 4; ++nt) {
                int row = nt * 16 + r;
                int sw = (row & 7) << 3;
                bfrag vf0 = *(const bfrag*)&Vs[row * 64 + ((g * 8) ^ sw)];
                bfrag vf1 = *(const bfrag*)&Vs[row * 64 + ((32 + g * 8) ^ sw)];
                oacc[u][nt] = __builtin_amdgcn_mfma_f32_16x16x32_bf16(pa0, vf0, oacc[u][nt], 0, 0, 0);
                oacc[u][nt] = __builtin_amdgcn_mfma_f32_16x16x32_bf16(pa1, vf1, oacc[u][nt], 0, 0, 0);
            }
        }
    }

    #pragma unroll
    for (int u = 0; u < 2; ++u) {
        #pragma unroll
        for (int p = 0; p < 4; ++p) {
            float lp = __shfl(l[u], 20 * g + p, 64);
            float inv = 1.f / lp;
            int qrow = qbase + u * 16 + 4 * g + p;
            short* op = AO + ((size_t)(b * S_ + qrow)) * (NH_ * HD_) + h * HD_;
            #pragma unroll
            for (int nt = 0; nt < 4; ++nt)
                op[nt * 16 + r] = f2bf(oacc[u][nt][p] * inv);
        }
    }
}

extern "C" void kernel_launch(void* const* d_in, const int* in_sizes, int n_in,
                              void* d_out, int out_size, void* d_ws, size_t ws_size,
                              hipStream_t stream) {
    const float* hs   = (const float*)d_in[0];
    const float* kv_a = (const float*)d_in[1];
    const float* kv_b = (const float*)d_in[2];
    const float* o_w  = (const float*)d_in[3];
    float* out = (float*)d_out;
    char* w = (char*)d_ws;

    float* tab   = (float*)w;                 w += 524288;       // 2048*64 f32
    short* hs_bf = (short*)w;                 // aliased by AO after GEMM1
    short* AO    = (short*)w;                 w += 16777216;
    short* kvaT  = (short*)w;                 w += 2097152;      // 512 x 2048
    short* kvbT  = (short*)w;                 w += 524288;       // 512 x 512
    short* owT   = (short*)w;                 w += 8388608;      // 2048 x 2048
    short* C1    = (short*)w;                 w += 4194304;      // 4096 x 512 bf16
    float* KV    = (float*)w;                 w += 8388608;      // 4096 x 512 f32
    short* Kr    = (short*)w;                 w += 2097152;      // 2*4*2048*64 bf16
    short* Vv    = (short*)w;                 w += 2097152;
    short* Vb    = (short*)w;                 w += 2097152;

    rope_table_k<<<dim3(256), dim3(256), 0, stream>>>(tab);
    f2b_k<<<dim3(8192), dim3(256), 0, stream>>>(hs, hs_bf);

    transpose_f2b<<<dim3(16, 64), dim3(32, 8), 0, stream>>>(kv_a, kvaT, 2048, 512);
    transpose_f2b<<<dim3(16, 16), dim3(32, 8), 0, stream>>>(kv_b, kvbT, 512, 512);
    transpose_f2b<<<dim3(64, 64), dim3(32, 8), 0, stream>>>(o_w, owT, 2048, 2048);

    mgemm<true><<<dim3(4, 32), dim3(256), 0, stream>>>(hs_bf, kvaT, C1, 4096, 512, 2048);
    mgemm<false><<<dim3(4, 32), dim3(256), 0, stream>>>(C1, kvbT, KV, 4096, 512, 512);

    prep_kv_k<<<dim3(2048), dim3(256), 0, stream>>>(KV, tab, Kr, Vv);
    build_vb<<<dim3(32, 8), dim3(256), 0, stream>>>(Vv, Vb);

    attn_mfma<<<dim3(16, 32, 2), dim3(256), 0, stream>>>(hs, tab, Kr, Vb, AO);

    mgemm<false><<<dim3(16, 32), dim3(256), 0, stream>>>(AO, owT, out, 4096, 2048, 2048);
}

// Round 4
// 217.400 us; speedup vs baseline: 14.0341x; 1.3390x over previous
//
#include <hip/hip_runtime.h>
#include <hip/hip_bf16.h>
#include <math.h>

#define B_    2
#define S_    2048
#define HID_  2048
#define NH_   32
#define NKV_  4
#define HD_   64
#define NEGV  (-1e30f)

typedef __attribute__((ext_vector_type(8))) short bfrag;
typedef __attribute__((ext_vector_type(4))) float f32x4;

__device__ __forceinline__ short f2bf(float f) {
    unsigned u = __builtin_bit_cast(unsigned, f);
    u += 0x7FFFu + ((u >> 16) & 1u);
    return (short)(u >> 16);
}

__device__ __forceinline__ void glds16(const short* g, short* l) {
    __builtin_amdgcn_global_load_lds(
        (const __attribute__((address_space(1))) void*)(const void*)g,
        (__attribute__((address_space(3))) void*)(void*)l, 16, 0, 0);
}

// cos/sin table: tab[s*64+i]=cos, tab[s*64+32+i]=sin
__global__ void rope_table_k(float* __restrict__ tab) {
    int idx = blockIdx.x * blockDim.x + threadIdx.x;
    if (idx >= S_ * 32) return;
    int s = idx >> 5, i = idx & 31;
    float inv = 1.0f / powf(10000.0f, (float)(2 * i) / 64.0f);
    float ang = (float)s * inv;
    tab[s * 64 + i]      = cosf(ang);
    tab[s * 64 + 32 + i] = sinf(ang);
}

__global__ void f2b_k(const float* __restrict__ in, short* __restrict__ out) {
    int i = (blockIdx.x * blockDim.x + threadIdx.x) * 4;
    float4 v = *(const float4*)(in + i);
    short4 o;
    o.x = f2bf(v.x); o.y = f2bf(v.y); o.z = f2bf(v.z); o.w = f2bf(v.w);
    *(short4*)(out + i) = o;
}

// fp32 (R x C) -> bf16 transposed (C x R)
__global__ void transpose_f2b(const float* __restrict__ in, short* __restrict__ out,
                              int R, int C) {
    __shared__ float t[32][33];
    int c0 = blockIdx.x * 32, r0 = blockIdx.y * 32;
    int x = threadIdx.x, y = threadIdx.y;  // 32 x 8
    #pragma unroll
    for (int i = 0; i < 32; i += 8) t[y + i][x] = in[(size_t)(r0 + y + i) * C + c0 + x];
    __syncthreads();
    #pragma unroll
    for (int i = 0; i < 32; i += 8)
        out[(size_t)(c0 + y + i) * R + r0 + x] = f2bf(t[x][y + i]);
}

// KV fp32 (b,s,512) -> RoPE'd K bf16 (b,kvh,s,64) XOR-swizzled + V bf16 natural
__global__ void prep_kv_k(const float* __restrict__ kv, const float* __restrict__ tab,
                          short* __restrict__ Kr, short* __restrict__ Vv) {
    int idx = blockIdx.x * blockDim.x + threadIdx.x;
    int i = idx & 31;
    int r = idx >> 5;
    int s = r & (S_ - 1);
    int bk = r >> 11;
    int kvh = bk & (NKV_ - 1);
    int b = bk >> 2;
    const float* src = kv + ((size_t)(b * S_ + s)) * 512 + kvh * 128;
    float k1 = src[i], k2 = src[i + 32];
    float v1 = src[64 + i], v2 = src[96 + i];
    float c = tab[s * 64 + i], sn = tab[s * 64 + 32 + i];
    size_t dst = (size_t)r * 64;
    int swz = (s & 7) << 3;
    Kr[dst + (i ^ swz)]        = f2bf(k1 * c - k2 * sn);
    Kr[dst + ((i + 32) ^ swz)] = f2bf(k2 * c + k1 * sn);
    Vv[dst + i]      = f2bf(v1);
    Vv[dst + 32 + i] = f2bf(v2);
}

// Build blocked V: Vb[(bk,kt)][d=64][c=64], column c holds V[kv=sigma(c)][d],
// XOR-swizzled by row d. sigma matches PV A-frag kv-slot order.
__global__ void build_vb(const short* __restrict__ Vv, short* __restrict__ Vb) {
    int kt = blockIdx.x, bk = blockIdx.y;
    const short* src = Vv + ((size_t)bk * S_ + kt * 64) * 64;
    short* dst = Vb + ((size_t)(bk * 32 + kt)) * 4096;
    int t = threadIdx.x;
    int d = t >> 2;
    int cb = (t & 3) * 16;
    int swz = (d & 7) << 3;
    #pragma unroll
    for (int ii = 0; ii < 16; ++ii) {
        int c = cb + ii;
        int kvl = (c & 3) | (((c >> 3) & 3) << 2) | (((c >> 2) & 1) << 4) | (c & 32);
        dst[d * 64 + (c ^ swz)] = src[(size_t)kvl * 64 + d];
    }
}

// bf16 MFMA GEMM: C[M,N] = A[M,K] @ Bt[N,K]^T. 128 x BN tile, BK=32,
// global_load_lds staging, 2-phase double buffer.
template<int BN, bool OUT_BF16>
__global__ __launch_bounds__(256)
void mgemm(const short* __restrict__ A, const short* __restrict__ Bt,
           void* __restrict__ Cout, int M, int N, int K) {
    __shared__ short As[2][128][32];
    __shared__ short Bs[2][BN][32];
    const int tid = threadIdx.x;
    const int wv = tid >> 6, lane = tid & 63;
    const int g = lane >> 4, r = lane & 15;
    constexpr int MI = (BN == 128) ? 4 : 2;
    const int rowb = (BN == 128) ? (wv >> 1) * 64 : wv * 32;
    const int colb = (BN == 128) ? (wv & 1) * 64 : 0;
    const int row0 = blockIdx.y * 128;
    const int col0 = blockIdx.x * BN;

    f32x4 acc[MI][4];
    #pragma unroll
    for (int i = 0; i < MI; ++i)
        #pragma unroll
        for (int j = 0; j < 4; ++j) { f32x4 z = {0.f,0.f,0.f,0.f}; acc[i][j] = z; }

    const int srow = tid >> 2;          // 0..63
    const int schk = (tid & 3) * 8;     // 0,8,16,24
    const short* Asrc = A + (size_t)(row0 + srow) * K + schk;
    const short* Bsrc = Bt + (size_t)(col0 + srow) * K + schk;

    const int nk = K >> 5;
    // prologue
    {
        glds16(Asrc, &As[0][srow][schk]);
        glds16(Asrc + (size_t)64 * K, &As[0][srow + 64][schk]);
        glds16(Bsrc, &Bs[0][srow][schk]);
        if (BN == 128) glds16(Bsrc + (size_t)64 * K, &Bs[0][srow + 64][schk]);
    }
    __syncthreads();

    for (int t = 0; t < nk; ++t) {
        const int buf = t & 1;
        if (t + 1 < nk) {
            const int k0 = (t + 1) << 5;
            glds16(Asrc + k0, &As[buf ^ 1][srow][schk]);
            glds16(Asrc + (size_t)64 * K + k0, &As[buf ^ 1][srow + 64][schk]);
            glds16(Bsrc + k0, &Bs[buf ^ 1][srow][schk]);
            if (BN == 128) glds16(Bsrc + (size_t)64 * K + k0, &Bs[buf ^ 1][srow + 64][schk]);
        }
        bfrag af[MI], bf[4];
        #pragma unroll
        for (int i = 0; i < MI; ++i) af[i] = *(const bfrag*)&As[buf][rowb + i * 16 + r][g * 8];
        #pragma unroll
        for (int j = 0; j < 4; ++j) bf[j] = *(const bfrag*)&Bs[buf][colb + j * 16 + r][g * 8];
        #pragma unroll
        for (int i = 0; i < MI; ++i)
            #pragma unroll
            for (int j = 0; j < 4; ++j)
                acc[i][j] = __builtin_amdgcn_mfma_f32_16x16x32_bf16(af[i], bf[j], acc[i][j], 0, 0, 0);
        __syncthreads();
    }

    #pragma unroll
    for (int i = 0; i < MI; ++i) {
        int row = row0 + rowb + i * 16 + g * 4;
        #pragma unroll
        for (int j = 0; j < 4; ++j) {
            int col = col0 + colb + j * 16 + r;
            #pragma unroll
            for (int q = 0; q < 4; ++q) {
                float v = acc[i][j][q];
                if (OUT_BF16) ((short*)Cout)[(size_t)(row + q) * N + col] = f2bf(v);
                else          ((float*)Cout)[(size_t)(row + q) * N + col] = v;
            }
        }
    }
}

// Flash attention, swapped-QK^T bf16 MFMA, double-buffered K/V, balanced blocks.
// Block = 4 waves; wave = 32 q rows. grid (8, NH, B); block bx does qc=bx and 15-bx.
__global__ __launch_bounds__(256)
void attn_mfma(const float* __restrict__ hs, const float* __restrict__ tab,
               const short* __restrict__ Kr, const short* __restrict__ Vb,
               short* __restrict__ AO) {
    const int bx = blockIdx.x, h = blockIdx.y, b = blockIdx.z;
    const int kvh = h >> 3;
    const int tid = threadIdx.x;
    const int wv = tid >> 6, lane = tid & 63;
    const int g = lane >> 4, r = lane & 15;

    __shared__ short Ks[2][4096];
    __shared__ short Vs[2][4096];

    const short* ksrc = Kr + ((size_t)(b * NKV_ + kvh)) * S_ * 64;
    const short* vsrc = Vb + ((size_t)(b * NKV_ + kvh)) * 32 * 4096;

    #pragma unroll 1
    for (int pass = 0; pass < 2; ++pass) {
        const int qc = pass ? (15 - bx) : bx;
        const int qbase = qc * 128 + wv * 32;

        // Q fragments (RoPE + scale folded)
        bfrag qf[2][2];
        #pragma unroll
        for (int u = 0; u < 2; ++u) {
            int q = qbase + u * 16 + r;
            const float* hq = hs + ((size_t)(b * S_ + q)) * HID_ + h * HD_;
            const float* ct = tab + (size_t)q * 64;
            float4 x1a = *(const float4*)(hq + g * 8);
            float4 x1b = *(const float4*)(hq + g * 8 + 4);
            float4 x2a = *(const float4*)(hq + 32 + g * 8);
            float4 x2b = *(const float4*)(hq + 32 + g * 8 + 4);
            float4 ca  = *(const float4*)(ct + g * 8);
            float4 cb  = *(const float4*)(ct + g * 8 + 4);
            float4 sa4 = *(const float4*)(ct + 32 + g * 8);
            float4 sb4 = *(const float4*)(ct + 32 + g * 8 + 4);
            float x1[8] = {x1a.x,x1a.y,x1a.z,x1a.w,x1b.x,x1b.y,x1b.z,x1b.w};
            float x2[8] = {x2a.x,x2a.y,x2a.z,x2a.w,x2b.x,x2b.y,x2b.z,x2b.w};
            float cc[8] = {ca.x,ca.y,ca.z,ca.w,cb.x,cb.y,cb.z,cb.w};
            float ss[8] = {sa4.x,sa4.y,sa4.z,sa4.w,sb4.x,sb4.y,sb4.z,sb4.w};
            #pragma unroll
            for (int j = 0; j < 8; ++j) {
                qf[u][0][j] = f2bf((x1[j] * cc[j] - x2[j] * ss[j]) * 0.125f);
                qf[u][1][j] = f2bf((x2[j] * cc[j] + x1[j] * ss[j]) * 0.125f);
            }
        }

        f32x4 oacc[2][4];
        #pragma unroll
        for (int u = 0; u < 2; ++u)
            #pragma unroll
            for (int i = 0; i < 4; ++i) { f32x4 z = {0.f,0.f,0.f,0.f}; oacc[u][i] = z; }
        float m[2] = {NEGV, NEGV}, l[2] = {0.f, 0.f};

        const int ntile = qc * 2 + 2;

        // prologue stage tile 0 into buf 0
        glds16(ksrc + (size_t)0 + tid * 8,        &Ks[0][tid * 8]);
        glds16(ksrc + (size_t)2048 + tid * 8,     &Ks[0][2048 + tid * 8]);
        glds16(vsrc + (size_t)0 + tid * 8,        &Vs[0][tid * 8]);
        glds16(vsrc + (size_t)2048 + tid * 8,     &Vs[0][2048 + tid * 8]);
        __syncthreads();

        #pragma unroll 1
        for (int kt = 0; kt < ntile; ++kt) {
            const int k0 = kt * 64;
            const int buf = kt & 1;
            if (kt + 1 < ntile) {
                const size_t nb = (size_t)(kt + 1) * 4096;
                glds16(ksrc + nb + tid * 8,        &Ks[buf ^ 1][tid * 8]);
                glds16(ksrc + nb + 2048 + tid * 8, &Ks[buf ^ 1][2048 + tid * 8]);
                glds16(vsrc + nb + tid * 8,        &Vs[buf ^ 1][tid * 8]);
                glds16(vsrc + nb + 2048 + tid * 8, &Vs[buf ^ 1][2048 + tid * 8]);
            }

            #pragma unroll
            for (int u = 0; u < 2; ++u) {
                if (k0 > qbase + u * 16 + 15) continue;   // fully masked subtile
                const int qg = qbase + u * 16 + r;
                // QK^T swapped: A=K rows(kv), B=Q cols(q)
                f32x4 sa[4];
                __builtin_amdgcn_s_setprio(1);
                #pragma unroll
                for (int nt = 0; nt < 4; ++nt) {
                    int row = nt * 16 + r;
                    int sw = (row & 7) << 3;
                    bfrag kf0 = *(const bfrag*)&Ks[buf][row * 64 + ((g * 8) ^ sw)];
                    bfrag kf1 = *(const bfrag*)&Ks[buf][row * 64 + ((32 + g * 8) ^ sw)];
                    f32x4 z = {0.f,0.f,0.f,0.f};
                    z = __builtin_amdgcn_mfma_f32_16x16x32_bf16(kf0, qf[u][0], z, 0, 0, 0);
                    z = __builtin_amdgcn_mfma_f32_16x16x32_bf16(kf1, qf[u][1], z, 0, 0, 0);
                    sa[nt] = z;
                }
                __builtin_amdgcn_s_setprio(0);
                // causal mask (only near diagonal)
                if (k0 + 63 > qbase + u * 16) {
                    #pragma unroll
                    for (int nt = 0; nt < 4; ++nt) {
                        #pragma unroll
                        for (int p = 0; p < 4; ++p) {
                            int kvg = k0 + nt * 16 + 4 * g + p;
                            if (kvg > qg) sa[nt][p] = NEGV;
                        }
                    }
                }
                // online softmax: per-q over kv (4 g-group replicas reduced)
                float tm = NEGV;
                #pragma unroll
                for (int nt = 0; nt < 4; ++nt)
                    #pragma unroll
                    for (int p = 0; p < 4; ++p) tm = fmaxf(tm, sa[nt][p]);
                tm = fmaxf(tm, __shfl_xor(tm, 16, 64));
                tm = fmaxf(tm, __shfl_xor(tm, 32, 64));
                float mn = fmaxf(m[u], tm);
                float cf = __expf(m[u] - mn);
                m[u] = mn;
                float sum = 0.f;
                #pragma unroll
                for (int nt = 0; nt < 4; ++nt)
                    #pragma unroll
                    for (int p = 0; p < 4; ++p) {
                        float e = __expf(sa[nt][p] - mn);
                        sa[nt][p] = e;
                        sum += e;
                    }
                sum += __shfl_xor(sum, 16, 64);
                sum += __shfl_xor(sum, 32, 64);
                l[u] = l[u] * cf + sum;
                // pack P into A-frags (kv-slot order sigma matches Vb)
                bfrag pa0, pa1;
                #pragma unroll
                for (int j = 0; j < 8; ++j) {
                    pa0[j] = f2bf(sa[j >> 2][j & 3]);
                    pa1[j] = f2bf(sa[2 + (j >> 2)][j & 3]);
                }
                // rescale O
                float cfp[4];
                #pragma unroll
                for (int p = 0; p < 4; ++p) cfp[p] = __shfl(cf, 20 * g + p, 64);
                #pragma unroll
                for (int nt = 0; nt < 4; ++nt)
                    #pragma unroll
                    for (int p = 0; p < 4; ++p) oacc[u][nt][p] *= cfp[p];
                // PV
                __builtin_amdgcn_s_setprio(1);
                #pragma unroll
                for (int nt = 0; nt < 4; ++nt) {
                    int row = nt * 16 + r;
                    int sw = (row & 7) << 3;
                    bfrag vf0 = *(const bfrag*)&Vs[buf][row * 64 + ((g * 8) ^ sw)];
                    bfrag vf1 = *(const bfrag*)&Vs[buf][row * 64 + ((32 + g * 8) ^ sw)];
                    oacc[u][nt] = __builtin_amdgcn_mfma_f32_16x16x32_bf16(pa0, vf0, oacc[u][nt], 0, 0, 0);
                    oacc[u][nt] = __builtin_amdgcn_mfma_f32_16x16x32_bf16(pa1, vf1, oacc[u][nt], 0, 0, 0);
                }
                __builtin_amdgcn_s_setprio(0);
            }
            __syncthreads();
        }

        #pragma unroll
        for (int u = 0; u < 2; ++u) {
            #pragma unroll
            for (int p = 0; p < 4; ++p) {
                float lp = __shfl(l[u], 20 * g + p, 64);
                float inv = 1.f / lp;
                int qrow = qbase + u * 16 + 4 * g + p;
                short* op = AO + ((size_t)(b * S_ + qrow)) * (NH_ * HD_) + h * HD_;
                #pragma unroll
                for (int nt = 0; nt < 4; ++nt)
                    op[nt * 16 + r] = f2bf(oacc[u][nt][p] * inv);
            }
        }
    }
}

extern "C" void kernel_launch(void* const* d_in, const int* in_sizes, int n_in,
                              void* d_out, int out_size, void* d_ws, size_t ws_size,
                              hipStream_t stream) {
    const float* hs   = (const float*)d_in[0];
    const float* kv_a = (const float*)d_in[1];
    const float* kv_b = (const float*)d_in[2];
    const float* o_w  = (const float*)d_in[3];
    float* out = (float*)d_out;
    char* w = (char*)d_ws;

    float* tab   = (float*)w;                 w += 524288;       // 2048*64 f32
    short* hs_bf = (short*)w;                 // aliased by AO after GEMM1
    short* AO    = (short*)w;                 w += 16777216;
    short* kvaT  = (short*)w;                 w += 2097152;      // 512 x 2048
    short* kvbT  = (short*)w;                 w += 524288;       // 512 x 512
    short* owT   = (short*)w;                 w += 8388608;      // 2048 x 2048
    short* C1    = (short*)w;                 w += 4194304;      // 4096 x 512 bf16
    float* KV    = (float*)w;                 w += 8388608;      // 4096 x 512 f32
    short* Kr    = (short*)w;                 w += 2097152;      // 2*4*2048*64 bf16
    short* Vv    = (short*)w;                 w += 2097152;
    short* Vb    = (short*)w;                 w += 2097152;

    rope_table_k<<<dim3(256), dim3(256), 0, stream>>>(tab);
    f2b_k<<<dim3(8192), dim3(256), 0, stream>>>(hs, hs_bf);

    transpose_f2b<<<dim3(16, 64), dim3(32, 8), 0, stream>>>(kv_a, kvaT, 2048, 512);
    transpose_f2b<<<dim3(16, 16), dim3(32, 8), 0, stream>>>(kv_b, kvbT, 512, 512);
    transpose_f2b<<<dim3(64, 64), dim3(32, 8), 0, stream>>>(o_w, owT, 2048, 2048);

    mgemm<64,true><<<dim3(8, 32), dim3(256), 0, stream>>>(hs_bf, kvaT, C1, 4096, 512, 2048);
    mgemm<64,false><<<dim3(8, 32), dim3(256), 0, stream>>>(C1, kvbT, KV, 4096, 512, 512);

    prep_kv_k<<<dim3(2048), dim3(256), 0, stream>>>(KV, tab, Kr, Vv);
    build_vb<<<dim3(32, 8), dim3(256), 0, stream>>>(Vv, Vb);

    attn_mfma<<<dim3(8, 32, 2), dim3(256), 0, stream>>>(hs, tab, Kr, Vb, AO);

    mgemm<128,false><<<dim3(16, 32), dim3(256), 0, stream>>>(AO, owT, out, 4096, 2048, 2048);
}